// Round 11
// baseline (220.871 us; speedup 1.0000x reference)
//
#include <hip/hip_runtime.h>

#define HW 4096
#define EPSV 1e-5f
#define SCL (0.125f * 1.44269504088896341f)   // 1/sqrt(64) * log2(e): softmax in exp2 domain

typedef unsigned short u16;
typedef unsigned int u32;
typedef __attribute__((ext_vector_type(8))) short short8;    // 8 bf16 (4 VGPRs)
typedef __attribute__((ext_vector_type(4))) short short4v;   // 4 bf16
typedef __attribute__((ext_vector_type(4))) float f32x4;
typedef __attribute__((ext_vector_type(16))) float f32x16;   // 32x32 C/D frag
typedef __attribute__((ext_vector_type(4))) int int4v;

#define MFMA_K32(a, b, c) __builtin_amdgcn_mfma_f32_16x16x32_bf16((a), (b), (c), 0, 0, 0)
#if __has_builtin(__builtin_amdgcn_mfma_f32_32x32x16_bf16)
#define MFMA32(a, b, c) __builtin_amdgcn_mfma_f32_32x32x16_bf16((a), (b), (c), 0, 0, 0)
#else
// Host-pass parse stub only: device pass has the builtin (gfx950).
#define MFMA32(a, b, c) (c)
#endif

#define GLDS(g, l) __builtin_amdgcn_global_load_lds( \
    (const __attribute__((address_space(1))) u16*)(g), \
    (__attribute__((address_space(3))) u16*)(l), 16, 0, 0)

__device__ __forceinline__ u16 f2b(float f) {
    u32 u = __float_as_uint(f);
    u32 r = (u + 0x7FFFu + ((u >> 16) & 1u)) >> 16;
    return (u16)r;
}

// ---------------- GroupNorm stage A: 512 blocks, partial sums ----------------
__global__ __launch_bounds__(256) void gn_partial(const float* __restrict__ x, float* __restrict__ ps) {
    int bid = blockIdx.x;
    const float4* base = (const float4*)x + (size_t)bid * 2048;
    int t = threadIdx.x;
    float s = 0.f, sq = 0.f;
    for (int i = t; i < 2048; i += 256) {
        float4 v = base[i];
        s += v.x + v.y + v.z + v.w;
        sq += v.x * v.x + v.y * v.y + v.z * v.z + v.w * v.w;
    }
    __shared__ float rs[256], rq[256];
    rs[t] = s; rq[t] = sq;
    __syncthreads();
    for (int o = 128; o > 0; o >>= 1) {
        if (t < o) { rs[t] += rs[t + o]; rq[t] += rq[t + o]; }
        __syncthreads();
    }
    if (t == 0) { ps[2 * bid] = rs[0]; ps[2 * bid + 1] = rq[0]; }
}

// ---------------- GroupNorm stage B: finalize 32 groups ----------------
__global__ __launch_bounds__(64) void gn_final(const float* __restrict__ ps, float* __restrict__ stats) {
    int t = threadIdx.x;
    if (t < 32) {
        float s = 0.f, sq = 0.f;
        for (int i = 0; i < 16; i++) {
            s += ps[2 * (t * 16 + i)];
            sq += ps[2 * (t * 16 + i) + 1];
        }
        float mean = s * (1.f / 131072.f);
        float var = sq * (1.f / 131072.f) - mean * mean;
        stats[t] = mean;
        stats[32 + t] = rsqrtf(var + EPSV);
    }
}

// ---------------- weight fp32 -> bf16 (rows < nscaled get * SCL) ----------------
__global__ __launch_bounds__(256) void wconv(const float* __restrict__ src, u16* __restrict__ dst, int nscaled) {
    int idx = blockIdx.x * 256 + threadIdx.x;
    int row = idx >> 6;
    float sc = (row < nscaled) ? SCL : 1.0f;
    float4 v = *((const float4*)src + idx);
    u32 lo = (u32)f2b(v.x * sc) | ((u32)f2b(v.y * sc) << 16);
    u32 hi = (u32)f2b(v.z * sc) | ((u32)f2b(v.w * sc) << 16);
    uint2 o; o.x = lo; o.y = hi;
    *(uint2*)(dst + (size_t)idx * 4) = o;
}

// ---------------- GroupNorm apply + transpose -> bf16 xt[n][p][c] ----------------
__global__ __launch_bounds__(256) void gn_apply_t(const float* __restrict__ x, const float* __restrict__ w,
                                                  const float* __restrict__ b, const float* __restrict__ stats,
                                                  u16* __restrict__ xt) {
    __shared__ u16 Tt[64][72];
    int t = threadIdx.x;
    int p0 = blockIdx.x * 64;
    int c0 = blockIdx.y * 64;
    int n = blockIdx.z;
    int pc = (t & 15) * 4;
#pragma unroll
    for (int jj = 0; jj < 4; jj++) {
        int r = (t >> 4) + jj * 16;
        int c = c0 + r;
        int grp = n * 8 + (c >> 5);
        float mean = stats[grp], rstd = stats[32 + grp];
        float a = rstd * w[c];
        float bb = b[c] - mean * a;
        float4 v = *(const float4*)(x + ((size_t)n * 256 + c) * HW + p0 + pc);
        Tt[pc + 0][r] = f2b(v.x * a + bb);
        Tt[pc + 1][r] = f2b(v.y * a + bb);
        Tt[pc + 2][r] = f2b(v.z * a + bb);
        Tt[pc + 3][r] = f2b(v.w * a + bb);
    }
    __syncthreads();
    int p = t >> 2, ck = t & 3;
    short8 s0 = *(const short8*)&Tt[p][ck * 16];
    short8 s1 = *(const short8*)&Tt[p][ck * 16 + 8];
    u16* dst = xt + ((size_t)n * HW + p0 + p) * 256 + c0 + ck * 16;
    *(short8*)dst = s0;
    *(short8*)(dst + 8) = s1;
}

// ---------------- QKV MFMA GEMM ----------------
__global__ __launch_bounds__(256) void qkv_mfma(const u16* __restrict__ xt, const u16* __restrict__ Wb,
                                                const float* __restrict__ bq, u16* __restrict__ Qw,
                                                u16* __restrict__ Kw, u16* __restrict__ Vw) {
    __shared__ u16 Xs[64 * 256];   // [p][c], chunk c/8 xor-swizzled by p&7
    int t = threadIdx.x;
    int w = t >> 6, lane = t & 63;
    int col = lane & 15, quad = lane >> 4;
    int p0 = blockIdx.x * 64;
    int o0 = blockIdx.y * 64;
    int n = blockIdx.z;

#pragma unroll
    for (int j = 0; j < 8; j++) {
        int rl = j * 2 + (lane >> 5);
        int row = w * 16 + rl;
        int slot = (lane & 31) ^ (rl & 7);
        GLDS(xt + ((size_t)n * HW + p0 + row) * 256 + slot * 8, Xs + (w * 16 + j * 2) * 256);
    }

    const u16* wrow = Wb + (size_t)(o0 + w * 16 + col) * 256 + quad * 8;
    short8 A[8];
#pragma unroll
    for (int ks = 0; ks < 8; ks++) A[ks] = *(const short8*)(wrow + ks * 32);

    __syncthreads();

    f32x4 C[4];
#pragma unroll
    for (int pb = 0; pb < 4; pb++) C[pb] = (f32x4){0.f, 0.f, 0.f, 0.f};
    int c7 = col & 7;
#pragma unroll
    for (int pb = 0; pb < 4; pb++) {
        const u16* xr = Xs + (pb * 16 + col) * 256;
#pragma unroll
        for (int ks = 0; ks < 8; ks++) {
            int slot = (ks * 4 + quad) ^ c7;
            short8 Bf = *(const short8*)(xr + slot * 8);
            C[pb] = MFMA_K32(A[ks], Bf, C[pb]);
        }
    }

    int type = o0 >> 8;
    int h = (o0 >> 6) & 3;
    int nh = n * 4 + h;
    float sc = (type == 0) ? SCL : 1.0f;
    if (type == 2) {
#pragma unroll
        for (int rg = 0; rg < 4; rg++) {
            int d = w * 16 + quad * 4 + rg;
            float bias = bq[o0 + d];
            u16* vb = Vw + ((size_t)nh * 64 + d) * HW + p0 + col;
#pragma unroll
            for (int pb = 0; pb < 4; pb++)
                vb[pb * 16] = f2b(C[pb][rg] + bias);
        }
    } else {
        u16* dst = (type == 0 ? Qw : Kw) + ((size_t)nh * HW + p0 + col) * 64 + w * 16 + quad * 4;
        float b0 = sc * bq[o0 + w * 16 + quad * 4 + 0];
        float b1 = sc * bq[o0 + w * 16 + quad * 4 + 1];
        float b2 = sc * bq[o0 + w * 16 + quad * 4 + 2];
        float b3 = sc * bq[o0 + w * 16 + quad * 4 + 3];
#pragma unroll
        for (int pb = 0; pb < 4; pb++) {
            uint2 o;
            o.x = (u32)f2b(C[pb][0] + b0) | ((u32)f2b(C[pb][1] + b1) << 16);
            o.y = (u32)f2b(C[pb][2] + b2) | ((u32)f2b(C[pb][3] + b3) << 16);
            *(uint2*)(dst + (size_t)(pb * 16) * 64) = o;
        }
    }
}

// ---------------- MFMA flash attention v7: 32x32x16 MFMAs throughout ----------------
// grid (32 q-tiles of 128, 16 nh), block 256 (4 waves). Wave: 32 q, 32 steps of j-tile 128.
// S^T 32x32 C-layout (row=(reg&3)+8(reg>>2)+4h, col=q) feeds PV B-frags (K=16) with zero
// lane exchange: PV chunk pv uses C regs [8(pv&1)..+7]. V^T A-frags use the matching
// permuted j-order (contraction is order-invariant) via 2x b64 reads.
// Swizzle key (r&7)^((r>>3)&3) on stage+read breaks 4-lane same-bank groups.
__global__ __launch_bounds__(256) void flash_mfma(const u16* __restrict__ Qw, const u16* __restrict__ Kw,
                                                  const u16* __restrict__ Vw, u16* __restrict__ attnT) {
    __shared__ u16 Ks[2][128 * 64];   // [j][d]
    __shared__ u16 Vts[2][64 * 128];  // [d][j]
    int t = threadIdx.x;
    int w = t >> 6, lane = t & 63;
    int l31 = lane & 31, h = lane >> 5;
    int q0 = blockIdx.x * 128;
    int nh = blockIdx.y;
    int key = (l31 & 7) ^ ((l31 >> 3) & 3);

    // Q B-frags: lane q = q0 + w*32 + l31, k-chunk c: d = c*16 + h*8 + i
    const u16* qp = Qw + ((size_t)nh * HW + q0 + w * 32 + l31) * 64 + h * 8;
    short8 Qb[4];
#pragma unroll
    for (int c = 0; c < 4; c++) Qb[c] = *(const short8*)(qp + c * 16);

    f32x16 Oc0 = (f32x16)(0.0f), Oc1 = (f32x16)(0.0f);
    float lsum = 0.f;

    const u16* kbase = Kw + (size_t)nh * HW * 64;  // [p][d]
    const u16* vbase = Vw + (size_t)nh * 64 * HW;  // [d][p]
    // K staging: lane = lr*8 + cc within a 8-row/1KB GLDS group
    int lrK = lane >> 3, ccK = lane & 7;
    size_t kSrcOff = (size_t)lrK * 64 + (((ccK ^ lrK ^ w) & 7) * 8);
    // V staging: lane = rv*16 + cv within a 4-row/1KB GLDS group
    int rvV = lane >> 4, cvV = lane & 15;

#define STAGE(jt_, b_) do { \
        int j0_ = (jt_) * 128; \
        _Pragma("unroll") \
        for (int s_ = 0; s_ < 4; s_++) \
            GLDS(kbase + (size_t)(j0_ + w * 8 + s_ * 32) * 64 + kSrcOff, &Ks[b_][(w * 8 + s_ * 32) * 64]); \
        _Pragma("unroll") \
        for (int m_ = 0; m_ < 4; m_++) { \
            int d_ = w * 16 + m_ * 4 + rvV; \
            int vk_ = (d_ & 7) ^ ((d_ >> 3) & 3); \
            GLDS(vbase + (size_t)d_ * HW + j0_ + ((cvV ^ vk_) * 8), &Vts[b_][(w * 16 + m_ * 4) * 128]); \
        } \
    } while (0)

    STAGE(0, 0);
    __syncthreads();

    for (int jt = 0; jt < 32; jt++) {
        int cur = jt & 1;
        if (jt < 31) STAGE(jt + 1, cur ^ 1);
        const u16* KsC = Ks[cur];
        const u16* VtC = Vts[cur];
        const u16* vr0 = VtC + l31 * 128 + 4 * h;          // dt=0 rows
        const u16* vr1 = vr0 + 32 * 128;                   // dt=1 rows

#pragma unroll
        for (int st = 0; st < 4; st++) {
            // S^T 32x32 tile: rows j = st*32 + C-row, cols q
            const u16* kr = KsC + (st * 32 + l31) * 64;
            f32x16 c = (f32x16)(0.0f);
#pragma unroll
            for (int kc = 0; kc < 4; kc++) {
                short8 ka = *(const short8*)(kr + (((kc * 2 + h) ^ key) * 8));
                c = MFMA32(ka, Qb[kc], c);
            }
            // maxless softmax: p = exp2(s); l per-lane; pack pairs (trunc to bf16)
            union { u32 u[4]; short8 s; } b0, b1;
            float lp = 0.f;
#pragma unroll
            for (int r = 0; r < 8; r += 2) {
                float p0 = __builtin_amdgcn_exp2f(c[r]);
                float p1 = __builtin_amdgcn_exp2f(c[r + 1]);
                lp += p0 + p1;
                b0.u[r >> 1] = (__float_as_uint(p0) >> 16) | (__float_as_uint(p1) & 0xFFFF0000u);
            }
#pragma unroll
            for (int r = 8; r < 16; r += 2) {
                float p0 = __builtin_amdgcn_exp2f(c[r]);
                float p1 = __builtin_amdgcn_exp2f(c[r + 1]);
                lp += p0 + p1;
                b1.u[(r - 8) >> 1] = (__float_as_uint(p0) >> 16) | (__float_as_uint(p1) & 0xFFFF0000u);
            }
            lsum += lp;
            // PV: pv = 2st (+1); A = V^T with matching permuted j-order (2x b64)
#pragma unroll
            for (int hf = 0; hf < 2; hf++) {
                int pv = 2 * st + hf;
                int s1 = ((2 * pv) ^ key) * 8;
                int s2 = ((2 * pv + 1) ^ key) * 8;
                short4v a00 = *(const short4v*)(vr0 + s1);
                short4v a01 = *(const short4v*)(vr0 + s2);
                short8 va0 = __builtin_shufflevector(a00, a01, 0, 1, 2, 3, 4, 5, 6, 7);
                short4v a10 = *(const short4v*)(vr1 + s1);
                short4v a11 = *(const short4v*)(vr1 + s2);
                short8 va1 = __builtin_shufflevector(a10, a11, 0, 1, 2, 3, 4, 5, 6, 7);
                if (hf == 0) {
                    Oc0 = MFMA32(va0, b0.s, Oc0);
                    Oc1 = MFMA32(va1, b0.s, Oc1);
                } else {
                    Oc0 = MFMA32(va0, b1.s, Oc0);
                    Oc1 = MFMA32(va1, b1.s, Oc1);
                }
            }
        }
        __syncthreads();
    }
#undef STAGE

    // l: lanes (l31, h) and (l31, h^1) share q
    lsum += __shfl_xor(lsum, 32);
    float rl = 1.0f / lsum;

    // epilogue: O^T row d = (reg&3)+8(reg>>2)+4h+32dt, col q -> attnT[n][q][head*64+d]
    u16* ab = attnT + ((size_t)(nh >> 2) * HW + q0 + w * 32 + l31) * 256 + (nh & 3) * 64 + 4 * h;
#pragma unroll
    for (int dt = 0; dt < 2; dt++) {
#pragma unroll
        for (int g = 0; g < 4; g++) {
            float v0, v1, v2, v3;
            if (dt == 0) { v0 = Oc0[4*g]; v1 = Oc0[4*g+1]; v2 = Oc0[4*g+2]; v3 = Oc0[4*g+3]; }
            else         { v0 = Oc1[4*g]; v1 = Oc1[4*g+1]; v2 = Oc1[4*g+2]; v3 = Oc1[4*g+3]; }
            uint2 o;
            o.x = (u32)f2b(v0 * rl) | ((u32)f2b(v1 * rl) << 16);
            o.y = (u32)f2b(v2 * rl) | ((u32)f2b(v3 * rl) << 16);
            *(uint2*)(ab + dt * 32 + g * 8) = o;
        }
    }
}

// ---------------- Proj MFMA GEMM + bias + residual + mask ----------------
__global__ __launch_bounds__(256) void proj_mfma(const u16* __restrict__ attnT, const u16* __restrict__ Wpb,
                                                 const float* __restrict__ bp, const float* __restrict__ x,
                                                 const float* __restrict__ mask, float* __restrict__ out) {
    __shared__ u16 Xs[64 * 256];
    int t = threadIdx.x;
    int w = t >> 6, lane = t & 63;
    int col = lane & 15, quad = lane >> 4;
    int p0 = blockIdx.x * 64;
    int o0 = blockIdx.y * 64;
    int n = blockIdx.z;

#pragma unroll
    for (int j = 0; j < 8; j++) {
        int rl = j * 2 + (lane >> 5);
        int row = w * 16 + rl;
        int slot = (lane & 31) ^ (rl & 7);
        GLDS(attnT + ((size_t)n * HW + p0 + row) * 256 + slot * 8, Xs + (w * 16 + j * 2) * 256);
    }

    const u16* wrow = Wpb + (size_t)(o0 + w * 16 + col) * 256 + quad * 8;
    short8 A[8];
#pragma unroll
    for (int ks = 0; ks < 8; ks++) A[ks] = *(const short8*)(wrow + ks * 32);

    __syncthreads();

    f32x4 C[4];
#pragma unroll
    for (int pb = 0; pb < 4; pb++) C[pb] = (f32x4){0.f, 0.f, 0.f, 0.f};
    int c7 = col & 7;
#pragma unroll
    for (int pb = 0; pb < 4; pb++) {
        const u16* xr = Xs + (pb * 16 + col) * 256;
#pragma unroll
        for (int ks = 0; ks < 8; ks++) {
            int slot = (ks * 4 + quad) ^ c7;
            short8 Bf = *(const short8*)(xr + slot * 8);
            C[pb] = MFMA_K32(A[ks], Bf, C[pb]);
        }
    }

#pragma unroll
    for (int rg = 0; rg < 4; rg++) {
        int o = o0 + w * 16 + quad * 4 + rg;
        float bias = bp[o];
        const float* xb = x + ((size_t)n * 256 + o) * HW + p0 + col;
        float* ob = out + ((size_t)n * 256 + o) * HW + p0 + col;
        const float* mb = mask + (size_t)n * HW + p0 + col;
#pragma unroll
        for (int pb = 0; pb < 4; pb++) {
            float mv = mb[pb * 16];
            ob[pb * 16] = (xb[pb * 16] + C[pb][rg] + bias) * mv;
        }
    }
}

// ---------------- mask passthrough ----------------
__global__ __launch_bounds__(256) void mask_copy(const float* __restrict__ mask, float* __restrict__ out) {
    int i = blockIdx.x * 256 + threadIdx.x;
    out[i] = mask[i];
}

extern "C" void kernel_launch(void* const* d_in, const int* in_sizes, int n_in,
                              void* d_out, int out_size, void* d_ws, size_t ws_size,
                              hipStream_t stream) {
    const float* x = (const float*)d_in[0];
    const float* mask = (const float*)d_in[1];
    const float* norm_w = (const float*)d_in[2];
    const float* norm_b = (const float*)d_in[3];
    const float* qkv_w = (const float*)d_in[4];
    const float* qkv_b = (const float*)d_in[5];
    const float* proj_w = (const float*)d_in[6];
    const float* proj_b = (const float*)d_in[7];
    float* out = (float*)d_out;

    float* ws = (float*)d_ws;
    float* stats = ws;                    // 64 f32
    float* pstats = ws + 64;              // 1024 f32
    u16* xt = (u16*)(ws + 2048);          // 4,194,304 u16
    u16* Qw = xt + 4194304;
    u16* Kw = Qw + 4194304;
    u16* Vw = Kw + 4194304;
    u16* attnT = Vw + 4194304;
    u16* Wqb = attnT + 4194304;           // 196,608 u16
    u16* Wpb = Wqb + 196608;              // 65,536 u16

    gn_partial<<<512, 256, 0, stream>>>(x, pstats);
    gn_final<<<1, 64, 0, stream>>>(pstats, stats);
    wconv<<<192, 256, 0, stream>>>(qkv_w, Wqb, 256);   // 768*256/4 threads
    wconv<<<64, 256, 0, stream>>>(proj_w, Wpb, 0);     // 256*256/4 threads
    gn_apply_t<<<dim3(64, 4, 4), 256, 0, stream>>>(x, norm_w, norm_b, stats, xt);
    qkv_mfma<<<dim3(64, 12, 4), 256, 0, stream>>>(xt, Wqb, qkv_b, Qw, Kw, Vw);
    flash_mfma<<<dim3(32, 16), 256, 0, stream>>>(Qw, Kw, Vw, attnT);
    proj_mfma<<<dim3(64, 4, 4), 256, 0, stream>>>(attnT, Wpb, proj_b, x, mask, out);
    mask_copy<<<64, 256, 0, stream>>>(mask, out + 4194304);
}